// Round 9
// baseline (140.916 us; speedup 1.0000x reference)
//
#include <hip/hip_runtime.h>

// VectorQuantizer gfx950 R9: self-contained 256-row blocks, mi=4 (64 rows/wave),
// quarter-codebook LDS (256 codes, 37 KB) staged 4x -> 4 blocks/CU co-resident,
// de-phased, 4 waves/SIMD. Loss via plain per-block partials + tiny finalize
// kernel (no memset, no atomics, no zero-init).
// dist2[n,k] = ||x||^2 - 2 x.e_k + ||e_k||^2 ; argmin invariant to ||x||^2.
// A-frags hold bf16(-2x) (exact pow2 scale); MFMA C init = cc = 0.5+||e_k||^2
// so MFMA output IS s in ~[0.31,0.69] (>0 => IEEE bits order-monotonic).
// key = (bits(s) & ~1023) | code ; argmin = v_min_u32 ; ties -> lowest code.
// Loss: SSE_row = ||x||^2_fp32 + (s_win - 0.5); x read exactly once.
// CSTRIDE=68 (measured ~0 conflicts R4/R7; 72 regressed to 1M in R8).

typedef __attribute__((ext_vector_type(8))) short short8;
typedef __attribute__((ext_vector_type(4))) float f32x4;

#define VQ_D 64
#define CSTRIDE 68
#define ROWS_PER_BLOCK 256

__device__ inline unsigned short f2bf(float f) {
  union { float f; unsigned u; } v; v.f = f;
  unsigned r = v.u + 0x7FFFu + ((v.u >> 16) & 1u);  // RNE
  return (unsigned short)(r >> 16);
}

__global__ __launch_bounds__(256, 4) void vq_main(
    const float* __restrict__ x, const float* __restrict__ cb,
    float* __restrict__ out, float* __restrict__ partials) {
  __shared__ unsigned short cbs[256 * CSTRIDE];  // 34816 B
  __shared__ float c2s[256];                     // 1024 B
  __shared__ int idxs[ROWS_PER_BLOCK];           // 1024 B
  __shared__ float redbuf[4];

  const int tid = threadIdx.x;   // 0..255
  const int wave = tid >> 6;     // 0..3
  const int lane = tid & 63;
  const int quad = lane >> 4;
  const int col = lane & 15;
  const long blockRow0 = (long)blockIdx.x * ROWS_PER_BLOCK;
  const int waveRow0 = wave * 64;

  // ---- (a) A fragments: bf16(-2x), 64 rows/wave; fp32 ||x||^2 partial.
  short8 Af[4][2];
  float xsq = 0.f;
#pragma unroll
  for (int mi = 0; mi < 4; ++mi) {
#pragma unroll
    for (int ks = 0; ks < 2; ++ks) {
      long row = blockRow0 + waveRow0 + mi * 16 + col;
      const f32x4* xp = (const f32x4*)(x + row * VQ_D + ks * 32 + quad * 8);
      f32x4 lo = xp[0];
      f32x4 hi = xp[1];
      xsq += lo[0] * lo[0] + lo[1] * lo[1] + lo[2] * lo[2] + lo[3] * lo[3] +
             hi[0] * hi[0] + hi[1] * hi[1] + hi[2] * hi[2] + hi[3] * hi[3];
      short8 a;
      a[0] = (short)f2bf(-2.f * lo[0]); a[1] = (short)f2bf(-2.f * lo[1]);
      a[2] = (short)f2bf(-2.f * lo[2]); a[3] = (short)f2bf(-2.f * lo[3]);
      a[4] = (short)f2bf(-2.f * hi[0]); a[5] = (short)f2bf(-2.f * hi[1]);
      a[6] = (short)f2bf(-2.f * hi[2]); a[7] = (short)f2bf(-2.f * hi[3]);
      Af[mi][ks] = a;
    }
  }

  unsigned bk[4][4];
#pragma unroll
  for (int mi = 0; mi < 4; ++mi)
#pragma unroll
    for (int r = 0; r < 4; ++r) bk[mi][r] = 0xFFFFFFFFu;

  // ---- (b) 4 passes: stage 256 codes (fp32->bf16 + c2 via shuffles) -> 16-iter K-loop.
#pragma unroll 1
  for (int q = 0; q < 4; ++q) {
    if (q) __syncthreads();  // prior K-loop LDS reads complete before overwrite
    const float* src = cb + (size_t)q * 256 * VQ_D;
#pragma unroll
    for (int r = 0; r < 8; ++r) {
      int id = r * 256 + tid;  // code = id>>3, piece = id&7 (8 lanes per code)
      int code = id >> 3;
      int piece = id & 7;
      const f32x4* sp = (const f32x4*)(src + (size_t)code * VQ_D + piece * 8);
      f32x4 lo = sp[0];
      f32x4 hi = sp[1];
      short8 v;
      v[0] = (short)f2bf(lo[0]); v[1] = (short)f2bf(lo[1]);
      v[2] = (short)f2bf(lo[2]); v[3] = (short)f2bf(lo[3]);
      v[4] = (short)f2bf(hi[0]); v[5] = (short)f2bf(hi[1]);
      v[6] = (short)f2bf(hi[2]); v[7] = (short)f2bf(hi[3]);
      *(short8*)(cbs + code * CSTRIDE + piece * 8) = v;
      float p = lo[0] * lo[0] + lo[1] * lo[1] + lo[2] * lo[2] + lo[3] * lo[3] +
                hi[0] * hi[0] + hi[1] * hi[1] + hi[2] * hi[2] + hi[3] * hi[3];
      p += __shfl_xor(p, 1);
      p += __shfl_xor(p, 2);
      p += __shfl_xor(p, 4);
      if (piece == 0) c2s[code] = p + 0.5f;
    }
    __syncthreads();

    const unsigned short* bbase = cbs + (size_t)col * CSTRIDE + quad * 8;
    const unsigned cbase = (unsigned)(q << 8) | (unsigned)col;
#pragma unroll 4
    for (int t = 0; t < 16; ++t) {
      const unsigned short* bp = bbase + t * 16 * CSTRIDE;
      short8 b0 = *(const short8*)bp;
      short8 b1 = *(const short8*)(bp + 32);
      float cc = c2s[t * 16 + col];

      f32x4 acc[4];
#pragma unroll
      for (int mi = 0; mi < 4; ++mi) {
        f32x4 a = {cc, cc, cc, cc};
        a = __builtin_amdgcn_mfma_f32_16x16x32_bf16(Af[mi][0], b0, a, 0, 0, 0);
        a = __builtin_amdgcn_mfma_f32_16x16x32_bf16(Af[mi][1], b1, a, 0, 0, 0);
        acc[mi] = a;
      }

      const unsigned code = cbase | (unsigned)(t << 4);
#pragma unroll
      for (int mi = 0; mi < 4; ++mi)
#pragma unroll
        for (int r = 0; r < 4; ++r)
          bk[mi][r] = min(bk[mi][r], (__float_as_uint(acc[mi][r]) & 0xFFFFFC00u) | code);
    }
  }

  // ---- (c) Col-reduce keys (all 16 cols end with the row minimum).
#pragma unroll
  for (int off = 1; off < 16; off <<= 1) {
#pragma unroll
    for (int mi = 0; mi < 4; ++mi)
#pragma unroll
      for (int r = 0; r < 4; ++r) {
        unsigned o = (unsigned)__shfl_xor((int)bk[mi][r], off);
        bk[mi][r] = min(bk[mi][r], o);
      }
  }

  // s_win sum for the loss; each row duplicated on 16 cols -> x1/16.
  float ssum = 0.f;
#pragma unroll
  for (int mi = 0; mi < 4; ++mi)
#pragma unroll
    for (int r = 0; r < 4; ++r)
      ssum += __uint_as_float(bk[mi][r] & 0xFFFFFC00u) - 0.5f;

  // Per-wave idxs (same-wave LDS write->read; no block barrier needed).
  if (col == 0) {
#pragma unroll
    for (int mi = 0; mi < 4; ++mi)
#pragma unroll
      for (int r = 0; r < 4; ++r)
        idxs[waveRow0 + mi * 16 + quad * 4 + r] = (int)(bk[mi][r] & 1023u);
  }

  // ---- (d) Epilogue: gather winners from GLOBAL fp32 cb (L2-hot, exact rows).
  const f32x4* cb4 = (const f32x4*)cb;
  f32x4* out4 = (f32x4*)out;
#pragma unroll
  for (int i = 0; i < 16; ++i) {
    int c = i * 64 + lane;   // 0..1023 : row_l = c>>4 (0..63), d4 = c&15
    int row_l = c >> 4;
    int d4 = c & 15;
    int idx = idxs[waveRow0 + row_l];
    f32x4 cv = cb4[(size_t)idx * 16 + d4];
    long gi = (blockRow0 + waveRow0 + row_l) * 16 + d4;
    out4[gi] = cv;
  }

  // ---- (e) Loss partial: SSE_block = sum_rows ||x||^2 + sum_rows (s_win-0.5).
  float part = xsq + ssum * 0.0625f;
#pragma unroll
  for (int off = 32; off; off >>= 1) part += __shfl_down(part, off);
  if (lane == 0) redbuf[wave] = part;
  __syncthreads();
  if (tid == 0)
    partials[blockIdx.x] = redbuf[0] + redbuf[1] + redbuf[2] + redbuf[3];
}

// Finalize: sum 512 block partials -> loss scalar. One 256-thread block.
__global__ __launch_bounds__(256) void vq_fin(const float* __restrict__ partials,
                                              float* __restrict__ loss_out,
                                              long nelem) {
  __shared__ float redbuf[4];
  const int tid = threadIdx.x;
  float s = partials[tid] + partials[tid + 256];
#pragma unroll
  for (int off = 32; off; off >>= 1) s += __shfl_down(s, off);
  if ((tid & 63) == 0) redbuf[tid >> 6] = s;
  __syncthreads();
  if (tid == 0)
    loss_out[0] = 1.25f * (redbuf[0] + redbuf[1] + redbuf[2] + redbuf[3]) / (float)nelem;
}

extern "C" void kernel_launch(void* const* d_in, const int* in_sizes, int n_in,
                              void* d_out, int out_size, void* d_ws, size_t ws_size,
                              hipStream_t stream) {
  const float* x = (const float*)d_in[0];
  const float* cb = (const float*)d_in[1];
  float* out = (float*)d_out;

  const long n_elem = (long)in_sizes[0];        // 8388608
  const int nrows = (int)(n_elem / VQ_D);       // 131072
  const int nblocks = nrows / ROWS_PER_BLOCK;   // 512

  float* partials = (float*)d_ws;  // 512 floats, fully overwritten (no init needed)

  vq_main<<<dim3(nblocks), dim3(256), 0, stream>>>(x, cb, out, partials);
  vq_fin<<<dim3(1), dim3(256), 0, stream>>>(partials, out + n_elem, n_elem);
}